// Round 12
// baseline (59.643 us; speedup 1.0000x reference)
//
#include <hip/hip_runtime.h>
#include <stdint.h>

typedef unsigned long long u64;
typedef uint32_t u32;
typedef unsigned char u8;

#define B_ 4
#define N_ 300000
#define C_ 5
#define GX_ 512
#define GY_ 512
#define GZ_ 1
#define GTOT_ (GX_*GY_*GZ_)   // 262144 voxels per batch
#define NW_ (GTOT_/64)        // 4096 occupancy words per batch
#define MAXV_ 30000
#define MAXP_ 20
#define ROWS_ (B_*MAXV_)      // 120000
#define OUT0_ELEMS_ (C_*MAXP_*ROWS_)  // 12,000,000 f32 elements

__device__ __forceinline__ int voxel_lin(float x, float y, float z) {
    // Matches the precomputed reference (XLA CPU): divide-by-constant lowered
    // to multiply-by-reciprocal; 1/0.2f rounds to exactly 5.0f, 1/8 exact.
    // Verified empirically in round 5 (absmax 9.8e-4, pass).
    float qx = (x + 51.2f) * 5.0f;
    float qy = (y + 51.2f) * 5.0f;
    float qz = (z + 5.0f) * 0.125f;
    int cx = (int)floorf(qx);
    int cy = (int)floorf(qy);
    int cz = (int)floorf(qz);
    if (cx < 0 || cx >= GX_ || cy < 0 || cy >= GY_ || cz < 0 || cz >= GZ_) return -1;
    return (cz * GY_ + cy) * GX_ + cx;
}

// Pass 0: zero the occupancy flags (1 MB, wide uint4 stores).
__global__ void k_init(uint4* __restrict__ occF4) {
    int i = blockIdx.x * blockDim.x + threadIdx.x;  // 0..65535
    occF4[i] = make_uint4(0u, 0u, 0u, 0u);
}

// Pass 1: occupancy byte-flags (idempotent plain stores) + lin cache so
// k_scatter doesn't re-read the 24 MB point array or recompute voxel_lin.
__global__ void k_mark(const float* __restrict__ pts, u8* __restrict__ occF,
                       int* __restrict__ linb) {
    int i = blockIdx.x * blockDim.x + threadIdx.x;
    int b = blockIdx.y;
    if (i >= N_) return;
    const float* p = pts + ((size_t)b * N_ + i) * C_;
    int lin = voxel_lin(p[0], p[1], p[2]);
    linb[(size_t)b * N_ + i] = lin;
    if (lin >= 0) occF[(size_t)b * GTOT_ + lin] = (u8)1;
}

// Pass 2a (WIDE): one thread per voxel; wave ballot builds the u64 occupancy
// word; lane 0 packs {mask_lo, mask_hi, pop, 0} into the fused wordTab entry
// (one 16B record per word -> k_scatter does a single uint4 load per point).
// Spare threads also zero cnt2 (moved out of k_init).
__global__ void k_maskcnt(const u8* __restrict__ occF, uint4* __restrict__ wordTab,
                          u32* __restrict__ cnt2) {
    int i = blockIdx.x * blockDim.x + threadIdx.x;  // voxel id
    int b = blockIdx.y;
    u8 f = occF[(size_t)b * GTOT_ + i];
    u64 m = __ballot(f != 0);
    if ((threadIdx.x & 63) == 0) {
        int w = i >> 6;
        wordTab[(size_t)b * NW_ + w] =
            make_uint4((u32)m, (u32)(m >> 32), (u32)__popcll(m), 0u);
    }
    // fold cnt2 zeroing in (grid has 4.2M threads; cnt2 is 120000 u32)
    int g = (blockIdx.y * gridDim.x + blockIdx.x) * blockDim.x + threadIdx.x;
    if (g < ROWS_) cnt2[g] = 0u;
}

// Pass 2b (tiny, shfl-based): exclusive scan of word popcounts -> wordTab .w.
// 2 barriers instead of 20 (wave shfl scan + 16-wave combine).
__global__ __launch_bounds__(1024) void k_scan2(uint4* __restrict__ wordTab,
                                                u32* __restrict__ nOcc) {
    int b = blockIdx.x;
    int t = threadIdx.x;
    uint4* wt = wordTab + (size_t)b * NW_;
    uint4 q0 = wt[t * 4 + 0], q1 = wt[t * 4 + 1], q2 = wt[t * 4 + 2], q3 = wt[t * 4 + 3];
    u32 c0 = q0.z, c1 = q1.z, c2 = q2.z, c3 = q3.z;
    u32 tot = c0 + c1 + c2 + c3;
    u32 lane = t & 63, wv = t >> 6;
    u32 s = tot;  // becomes inclusive prefix within wave
    #pragma unroll
    for (int d = 1; d < 64; d <<= 1) {
        u32 u = __shfl_up(s, d, 64);
        if (lane >= (u32)d) s += u;
    }
    __shared__ u32 wsum[16];
    if (lane == 63) wsum[wv] = s;
    __syncthreads();
    if (t < 16) {
        u32 ws2 = wsum[t];
        #pragma unroll
        for (int d = 1; d < 16; d <<= 1) {
            u32 u = __shfl_up(ws2, d, 16);
            if (t >= d) ws2 += u;
        }
        wsum[t] = ws2;  // inclusive over waves
    }
    __syncthreads();
    u32 excl = ((wv > 0) ? wsum[wv - 1] : 0u) + (s - tot);
    u32* base = (u32*)wt;
    base[(t * 4 + 0) * 4 + 3] = excl;
    base[(t * 4 + 1) * 4 + 3] = excl + c0;
    base[(t * 4 + 2) * 4 + 3] = excl + c0 + c1;
    base[(t * 4 + 3) * 4 + 3] = excl + c0 + c1 + c2;
    if (t == 1023) nOcc[b] = wsum[15];
}

// Pass 3: scatter point indices into their voxel slot (<=20 kept; order fixed
// in k_out). One fused 16B wordTab load per point; atomic winner (r==0) also
// records the slot's voxel id (replaces the old per-voxel fill pass).
__global__ void k_scatter(const int* __restrict__ linb, const uint4* __restrict__ wordTab,
                          u32* __restrict__ cnt2, u32* __restrict__ idxbuf,
                          u32* __restrict__ voxOf) {
    int i = blockIdx.x * blockDim.x + threadIdx.x;
    int b = blockIdx.y;
    if (i >= N_) return;
    int lin = linb[(size_t)b * N_ + i];
    if (lin < 0) return;
    int w = lin >> 6, bit = lin & 63;
    uint4 q = wordTab[(size_t)b * NW_ + w];
    u32 off = q.w;
    if (off >= MAXV_) return;              // ~83% of points exit here
    u64 m = (u64)q.x | ((u64)q.y << 32);
    u32 slot = off + (u32)__popcll(m & ((1ull << bit) - 1ull));
    if (slot >= MAXV_) return;
    u32 r = atomicAdd(&cnt2[b * MAXV_ + slot], 1u);
    if (r == 0) voxOf[b * MAXV_ + slot] = (u32)lin;
    if (r < MAXP_) idxbuf[((size_t)b * MAXV_ + slot) * MAXP_ + r] = (u32)i;
}

// Pass 4: one thread per output row -> sort indices (stable order), write f32 outputs
__global__ void k_out(const float* __restrict__ pts, const float* __restrict__ nr,
                      const u32* __restrict__ voxOf, const u32* __restrict__ cnt2,
                      const u32* __restrict__ idxbuf, const u32* __restrict__ nOcc,
                      float* __restrict__ out0, float* __restrict__ out1) {
    int row = blockIdx.x * blockDim.x + threadIdx.x;
    if (row >= ROWS_) return;
    int b = row / MAXV_;
    int local = row - b * MAXV_;
    u32 nv = nOcc[b];
    bool valid = (u32)local < (nv < MAXV_ ? nv : (u32)MAXV_);
    u32 lin = 0;
    int n = 0;
    u32 idxs[MAXP_];
    if (valid) {
        lin = voxOf[row];
        n = (int)min(cnt2[row], (u32)MAXP_);
        for (int r = 0; r < n; ++r) idxs[r] = idxbuf[(size_t)row * MAXP_ + r];
        // insertion sort ascending -> reference's stable (original index) order
        for (int a = 1; a < n; ++a) {
            u32 key = idxs[a];
            int j = a - 1;
            while (j >= 0 && idxs[j] > key) { idxs[j + 1] = idxs[j]; --j; }
            idxs[j + 1] = key;
        }
    }
    // coors_batch row: [b, z, y, x] as float values (d_out is f32)
    float4 cr;
    cr.x = (float)b;
    if (valid) {
        int x = lin & (GX_ - 1);
        int y = (lin >> 9) & (GY_ - 1);
        int z = (int)(lin >> 18);
        cr.y = (float)z; cr.z = (float)y; cr.w = (float)x;
    } else {
        cr.y = -1.0f; cr.z = -1.0f; cr.w = -1.0f;
    }
    *(float4*)(out1 + (size_t)row * 4) = cr;
    // normalization params (dims 0..2 only)
    float s0 = nr[0], s1 = nr[1], s2 = nr[2];
    float d0 = nr[3] - nr[0], d1 = nr[4] - nr[1], d2 = nr[5] - nr[2];
    for (int p = 0; p < MAXP_; ++p) {
        float f0 = 0.f, f1 = 0.f, f2 = 0.f, f3 = 0.f, f4 = 0.f;
        if (p < n) {
            const float* pp = pts + ((size_t)b * N_ + idxs[p]) * C_;
            f0 = (pp[0] - s0) / d0;
            f1 = (pp[1] - s1) / d1;
            f2 = (pp[2] - s2) / d2;
            f3 = pp[3];
            f4 = pp[4];
        }
        // out0 layout: [1, C, MAXP, ROWS] -> ((c*MAXP)+p)*ROWS + row (coalesced across rows)
        out0[(0 * MAXP_ + p) * ROWS_ + row] = f0;
        out0[(1 * MAXP_ + p) * ROWS_ + row] = f1;
        out0[(2 * MAXP_ + p) * ROWS_ + row] = f2;
        out0[(3 * MAXP_ + p) * ROWS_ + row] = f3;
        out0[(4 * MAXP_ + p) * ROWS_ + row] = f4;
    }
}

extern "C" void kernel_launch(void* const* d_in, const int* in_sizes, int n_in,
                              void* d_out, int out_size, void* d_ws, size_t ws_size,
                              hipStream_t stream) {
    const float* pts = (const float*)d_in[0];
    const float* nr  = (const float*)d_in[1];
    float* out0 = (float*)d_out;
    float* out1 = out0 + (size_t)OUT0_ELEMS_;

    uint8_t* ws = (uint8_t*)d_ws;
    // workspace layout (bytes), total 15,622,160 (ws is ~256 MiB per the
    // harness's 0xAA poison fill observed in round 8)
    uint4* wordTab = (uint4*)(ws + 0);        // 4*4096*16   = 262,144
    u32* voxOf     = (u32*)(ws + 262144);     // 120000*4    = 480,000
    u32* cnt2      = (u32*)(ws + 742144);     // 120000*4    = 480,000
    u32* idxbuf    = (u32*)(ws + 1222144);    // 120000*20*4 = 9,600,000
    int* linb      = (int*)(ws + 10822144);   // 4*300000*4  = 4,800,000
    u32* nOcc      = (u32*)(ws + 15622144);   // 4*4 = 16
    // occF (4*262144 = 1,048,576 bytes) aliases the head of idxbuf:
    // occF is dead after k_maskcnt; idxbuf is first written in k_scatter.
    u8*  occF      = (u8*)(ws + 1222144);

    dim3 gP((N_ + 255) / 256, B_);
    dim3 gV(GTOT_ / 256, B_);
    k_init   <<<(B_ * GTOT_ / 16 + 255) / 256, 256, 0, stream>>>((uint4*)occF);
    k_mark   <<<gP, 256, 0, stream>>>(pts, occF, linb);
    k_maskcnt<<<gV, 256, 0, stream>>>(occF, wordTab, cnt2);
    k_scan2  <<<B_, 1024, 0, stream>>>(wordTab, nOcc);
    k_scatter<<<gP, 256, 0, stream>>>(linb, wordTab, cnt2, idxbuf, voxOf);
    k_out    <<<(ROWS_ + 255) / 256, 256, 0, stream>>>(pts, nr, voxOf, cnt2, idxbuf, nOcc, out0, out1);
}

// Round 13
// 58.087 us; speedup vs baseline: 1.0268x; 1.0268x over previous
//
#include <hip/hip_runtime.h>
#include <stdint.h>

typedef unsigned long long u64;
typedef uint32_t u32;
typedef unsigned char u8;

#define B_ 4
#define N_ 300000
#define C_ 5
#define GX_ 512
#define GY_ 512
#define GZ_ 1
#define GTOT_ (GX_*GY_*GZ_)   // 262144 voxels per batch
#define NW_ (GTOT_/64)        // 4096 occupancy words per batch
#define MAXV_ 30000
#define MAXP_ 20
#define ROWS_ (B_*MAXV_)      // 120000
#define OUT0_ELEMS_ (C_*MAXP_*ROWS_)  // 12,000,000 f32 elements
#define NQ_ (N_/4)            // 75000 point-quads per batch (300000 % 4 == 0)

// init sizes in uint4 units
#define OCCF_Q_ (B_*GTOT_/16)   // 65536
#define CNT2_Q_ (ROWS_/4)       // 30000
#define INIT_Q_ (OCCF_Q_ + CNT2_Q_)  // 95536

__device__ __forceinline__ int voxel_lin(float x, float y, float z) {
    // Matches the precomputed reference (XLA CPU): divide-by-constant lowered
    // to multiply-by-reciprocal; 1/0.2f rounds to exactly 5.0f, 1/8 exact.
    // Verified empirically in round 5 (absmax 9.8e-4, pass).
    float qx = (x + 51.2f) * 5.0f;
    float qy = (y + 51.2f) * 5.0f;
    float qz = (z + 5.0f) * 0.125f;
    int cx = (int)floorf(qx);
    int cy = (int)floorf(qy);
    int cz = (int)floorf(qz);
    if (cx < 0 || cx >= GX_ || cy < 0 || cy >= GY_ || cz < 0 || cz >= GZ_) return -1;
    return (cz * GY_ + cy) * GX_ + cx;
}

// Pass 0: zero occF (1 MB) and cnt2 (480 KB) in one wide fill kernel.
__global__ void k_init(uint4* __restrict__ occF4, uint4* __restrict__ cnt2q) {
    int i = blockIdx.x * blockDim.x + threadIdx.x;
    if (i < OCCF_Q_) occF4[i] = make_uint4(0u, 0u, 0u, 0u);
    else if (i < INIT_Q_) cnt2q[i - OCCF_Q_] = make_uint4(0u, 0u, 0u, 0u);
}

// Pass 1: occupancy byte-flags + lin cache, 4 points per thread.
// 4 consecutive 20 B points = 5 aligned float4 loads; linb written as int4.
__global__ void k_mark(const float* __restrict__ pts, u8* __restrict__ occF,
                       int* __restrict__ linb) {
    int t = blockIdx.x * blockDim.x + threadIdx.x;
    int b = blockIdx.y;
    if (t >= NQ_) return;
    const float4* p4 = (const float4*)(pts + ((size_t)b * N_) * C_ + (size_t)t * 20);
    float4 a = p4[0], bb = p4[1], cc = p4[2], dd = p4[3], ee = p4[4];
    int4 L;
    L.x = voxel_lin(a.x,  a.y,  a.z);
    L.y = voxel_lin(bb.y, bb.z, bb.w);
    L.z = voxel_lin(cc.z, cc.w, dd.x);
    L.w = voxel_lin(dd.w, ee.x, ee.y);
    *(int4*)(linb + (size_t)b * N_ + (size_t)t * 4) = L;
    u8* of = occF + (size_t)b * GTOT_;
    if (L.x >= 0) of[L.x] = (u8)1;
    if (L.y >= 0) of[L.y] = (u8)1;
    if (L.z >= 0) of[L.z] = (u8)1;
    if (L.w >= 0) of[L.w] = (u8)1;
}

// Pass 2a (WIDE): one thread per voxel; wave ballot builds the u64 occupancy
// word for free; lane 0 writes the word and its popcount.
__global__ void k_maskcnt(const u8* __restrict__ occF, u64* __restrict__ occ,
                          u32* __restrict__ wordPop) {
    int i = blockIdx.x * blockDim.x + threadIdx.x;  // voxel id
    int b = blockIdx.y;
    u8 f = occF[(size_t)b * GTOT_ + i];
    u64 m = __ballot(f != 0);
    if ((threadIdx.x & 63) == 0) {
        int w = i >> 6;
        occ[(size_t)b * NW_ + w] = m;
        wordPop[(size_t)b * NW_ + w] = (u32)__popcll(m);
    }
}

// Pass 2b (tiny): exclusive scan of word popcounts; 64 KB total read.
__global__ __launch_bounds__(1024) void k_scan2(const u32* __restrict__ wordPop,
                                                u32* __restrict__ wordOff,
                                                u32* __restrict__ nOcc) {
    int b = blockIdx.x;
    int t = threadIdx.x;
    const uint4* wp = (const uint4*)(wordPop + (size_t)b * NW_);
    uint4 v = wp[t];
    __shared__ u32 sh[1024];
    sh[t] = v.x + v.y + v.z + v.w;
    __syncthreads();
    for (int off = 1; off < 1024; off <<= 1) {
        u32 u = (t >= off) ? sh[t - off] : 0u;
        __syncthreads();
        sh[t] += u;
        __syncthreads();
    }
    u32 excl = (t > 0) ? sh[t - 1] : 0u;
    u32* wo = wordOff + (size_t)b * NW_ + t * 4;
    wo[0] = excl;
    wo[1] = excl + v.x;
    wo[2] = excl + v.x + v.y;
    wo[3] = excl + v.x + v.y + v.z;
    if (t == 1023) nOcc[b] = sh[1023];
}

// Pass 3: scatter point indices into their voxel slot, 4 points per thread
// (int4 linb load). Atomic winner (r==0) records the slot's voxel id.
__global__ void k_scatter(const int* __restrict__ linb, const u64* __restrict__ occ,
                          const u32* __restrict__ wordOff,
                          u32* __restrict__ cnt2, u32* __restrict__ idxbuf,
                          u32* __restrict__ voxOf) {
    int t = blockIdx.x * blockDim.x + threadIdx.x;
    int b = blockIdx.y;
    if (t >= NQ_) return;
    int4 L = *(const int4*)(linb + (size_t)b * N_ + (size_t)t * 4);
    const u64* ob = occ + (size_t)b * NW_;
    const u32* wb = wordOff + (size_t)b * NW_;
    #pragma unroll
    for (int k = 0; k < 4; ++k) {
        int lin = (k == 0) ? L.x : (k == 1) ? L.y : (k == 2) ? L.z : L.w;
        if (lin < 0) continue;
        int w = lin >> 6, bit = lin & 63;
        u32 baseOff = wb[w];
        if (baseOff >= MAXV_) continue;    // ~83% of points exit here
        u64 m = ob[w];
        u32 slot = baseOff + (u32)__popcll(m & ((1ull << bit) - 1ull));
        if (slot >= MAXV_) continue;
        u32 r = atomicAdd(&cnt2[b * MAXV_ + slot], 1u);
        if (r == 0) voxOf[b * MAXV_ + slot] = (u32)lin;
        if (r < MAXP_) idxbuf[((size_t)b * MAXV_ + slot) * MAXP_ + r] = (u32)(t * 4 + k);
    }
}

// Pass 4: one thread per output row -> sort indices (stable order), write f32 outputs
__global__ void k_out(const float* __restrict__ pts, const float* __restrict__ nr,
                      const u32* __restrict__ voxOf, const u32* __restrict__ cnt2,
                      const u32* __restrict__ idxbuf, const u32* __restrict__ nOcc,
                      float* __restrict__ out0, float* __restrict__ out1) {
    int row = blockIdx.x * blockDim.x + threadIdx.x;
    if (row >= ROWS_) return;
    int b = row / MAXV_;
    int local = row - b * MAXV_;
    u32 nv = nOcc[b];
    bool valid = (u32)local < (nv < MAXV_ ? nv : (u32)MAXV_);
    u32 lin = 0;
    int n = 0;
    u32 idxs[MAXP_];
    if (valid) {
        lin = voxOf[row];
        n = (int)min(cnt2[row], (u32)MAXP_);
        // vectorized row read (row stride 80 B, 16B-aligned); entries >= n unused
        const uint4* ib = (const uint4*)(idxbuf + (size_t)row * MAXP_);
        uint4 q0 = ib[0], q1 = ib[1], q2 = ib[2], q3 = ib[3], q4 = ib[4];
        idxs[0]=q0.x; idxs[1]=q0.y; idxs[2]=q0.z; idxs[3]=q0.w;
        idxs[4]=q1.x; idxs[5]=q1.y; idxs[6]=q1.z; idxs[7]=q1.w;
        idxs[8]=q2.x; idxs[9]=q2.y; idxs[10]=q2.z; idxs[11]=q2.w;
        idxs[12]=q3.x; idxs[13]=q3.y; idxs[14]=q3.z; idxs[15]=q3.w;
        idxs[16]=q4.x; idxs[17]=q4.y; idxs[18]=q4.z; idxs[19]=q4.w;
        // insertion sort ascending -> reference's stable (original index) order
        for (int a = 1; a < n; ++a) {
            u32 key = idxs[a];
            int j = a - 1;
            while (j >= 0 && idxs[j] > key) { idxs[j + 1] = idxs[j]; --j; }
            idxs[j + 1] = key;
        }
    }
    // coors_batch row: [b, z, y, x] as float values (d_out is f32)
    float4 cr;
    cr.x = (float)b;
    if (valid) {
        int x = lin & (GX_ - 1);
        int y = (lin >> 9) & (GY_ - 1);
        int z = (int)(lin >> 18);
        cr.y = (float)z; cr.z = (float)y; cr.w = (float)x;
    } else {
        cr.y = -1.0f; cr.z = -1.0f; cr.w = -1.0f;
    }
    *(float4*)(out1 + (size_t)row * 4) = cr;
    // normalization params (dims 0..2 only)
    float s0 = nr[0], s1 = nr[1], s2 = nr[2];
    float d0 = nr[3] - nr[0], d1 = nr[4] - nr[1], d2 = nr[5] - nr[2];
    for (int p = 0; p < MAXP_; ++p) {
        float f0 = 0.f, f1 = 0.f, f2 = 0.f, f3 = 0.f, f4 = 0.f;
        if (p < n) {
            const float* pp = pts + ((size_t)b * N_ + idxs[p]) * C_;
            f0 = (pp[0] - s0) / d0;
            f1 = (pp[1] - s1) / d1;
            f2 = (pp[2] - s2) / d2;
            f3 = pp[3];
            f4 = pp[4];
        }
        // out0 layout: [1, C, MAXP, ROWS] -> ((c*MAXP)+p)*ROWS + row (coalesced across rows)
        out0[(0 * MAXP_ + p) * ROWS_ + row] = f0;
        out0[(1 * MAXP_ + p) * ROWS_ + row] = f1;
        out0[(2 * MAXP_ + p) * ROWS_ + row] = f2;
        out0[(3 * MAXP_ + p) * ROWS_ + row] = f3;
        out0[(4 * MAXP_ + p) * ROWS_ + row] = f4;
    }
}

extern "C" void kernel_launch(void* const* d_in, const int* in_sizes, int n_in,
                              void* d_out, int out_size, void* d_ws, size_t ws_size,
                              hipStream_t stream) {
    const float* pts = (const float*)d_in[0];
    const float* nr  = (const float*)d_in[1];
    float* out0 = (float*)d_out;
    float* out1 = out0 + (size_t)OUT0_ELEMS_;

    uint8_t* ws = (uint8_t*)d_ws;
    // workspace layout (bytes), total 15,622,160
    u64* occ     = (u64*)(ws + 0);            // 4*4096*8    = 131,072
    u32* wordOff = (u32*)(ws + 131072);       // 4*4096*4    =  65,536
    u32* voxOf   = (u32*)(ws + 196608);       // 120000*4    = 480,000
    u32* cnt2    = (u32*)(ws + 676608);       // 120000*4    = 480,000
    u32* idxbuf  = (u32*)(ws + 1156608);      // 120000*20*4 = 9,600,000
    int* linb    = (int*)(ws + 10756608);     // 4*300000*4  = 4,800,000
    u32* wordPop = (u32*)(ws + 15556608);     // 4*4096*4    =  65,536
    u32* nOcc    = (u32*)(ws + 15622144);     // 4*4 = 16
    // occF (4*262144 = 1,048,576 bytes) aliases the head of idxbuf:
    // occF is dead after k_maskcnt; idxbuf is first written in k_scatter.
    u8*  occF    = (u8*)(ws + 1156608);

    dim3 gQ((NQ_ + 255) / 256, B_);
    dim3 gV(GTOT_ / 256, B_);
    k_init   <<<(INIT_Q_ + 255) / 256, 256, 0, stream>>>((uint4*)occF, (uint4*)cnt2);
    k_mark   <<<gQ, 256, 0, stream>>>(pts, occF, linb);
    k_maskcnt<<<gV, 256, 0, stream>>>(occF, occ, wordPop);
    k_scan2  <<<B_, 1024, 0, stream>>>(wordPop, wordOff, nOcc);
    k_scatter<<<gQ, 256, 0, stream>>>(linb, occ, wordOff, cnt2, idxbuf, voxOf);
    k_out    <<<(ROWS_ + 255) / 256, 256, 0, stream>>>(pts, nr, voxOf, cnt2, idxbuf, nOcc, out0, out1);
}